// Round 2
// baseline (1808.690 us; speedup 1.0000x reference)
//
#include <hip/hip_runtime.h>
#include <hip/hip_bf16.h>
#include <stdint.h>

typedef __hip_bfloat16 bf16;
typedef __attribute__((ext_vector_type(8))) __bf16 bf16x8;
typedef __attribute__((ext_vector_type(4))) float f32x4;

__device__ __forceinline__ float bf2f(bf16 v) { return __bfloat162float(v); }
__device__ __forceinline__ bf16 f2bf(float v) { return __float2bfloat16(v); }

struct bf4 { bf16 a, b, c, d; };   // 8-byte packed store

// f32 -> bf16 converter, 4 elems/thread (n4 = n/4)
__global__ __launch_bounds__(256) void f2b_kernel(
    const float* __restrict__ s, bf16* __restrict__ d, int n4)
{
    int i = blockIdx.x * 256 + threadIdx.x;
    if (i >= n4) return;
    float4 v = ((const float4*)s)[i];
    bf4 o;
    o.a = f2bf(v.x); o.b = f2bf(v.y); o.c = f2bf(v.z); o.d = f2bf(v.w);
    ((bf4*)d)[i] = o;
}

#define BM 128
#define BN 128
#define BK 64
#define LDSS 72   // 64 + 8 pad -> 144B row stride (16B aligned), 2-way bank alias = free

// C[m,n] = sum_k A[m,k]*B[n,k]  (A row-major [M,K], B row-major [N,K]); C stored bf16 [M,ldc]
// ACT==1: C = softplus(v + bias[n])   (bias is f32)
template <int ACT>
__global__ __launch_bounds__(256) void gemm_bt(
    const bf16* __restrict__ A, const bf16* __restrict__ B,
    const float* __restrict__ bias, bf16* __restrict__ C,
    int M, int N, int K, int lda, int ldb, int ldc)
{
    __shared__ bf16 As[BM * LDSS];
    __shared__ bf16 Bs[BN * LDSS];

    const int tid  = threadIdx.x;
    const int wave = tid >> 6;
    const int lane = tid & 63;
    const int m0 = blockIdx.x * BM;
    const int n0 = blockIdx.y * BN;
    const int wm = (wave >> 1) * 64;
    const int wn = (wave & 1) * 64;

    f32x4 acc[4][4];
#pragma unroll
    for (int i = 0; i < 4; ++i)
#pragma unroll
        for (int j = 0; j < 4; ++j)
#pragma unroll
            for (int r = 0; r < 4; ++r) acc[i][j][r] = 0.f;

    const int srow = tid >> 3;          // 0..31
    const int scol = (tid & 7) * 8;     // 0..56 step 8

    for (int k0 = 0; k0 < K; k0 += BK) {
#pragma unroll
        for (int p = 0; p < 4; ++p) {
            int row = p * 32 + srow;
            {   // A tile
                bf16x8 v;
#pragma unroll
                for (int j = 0; j < 8; ++j) v[j] = (__bf16)0.f;
                int gm = m0 + row;
                if (gm < M) {
                    const bf16* src = A + (size_t)gm * lda + k0 + scol;
                    if (k0 + scol + 8 <= K) {
                        v = *(const bf16x8*)src;
                    } else {
#pragma unroll
                        for (int j = 0; j < 8; ++j)
                            if (k0 + scol + j < K) v[j] = ((const __bf16*)src)[j];
                    }
                }
                *(bf16x8*)(&As[row * LDSS + scol]) = v;
            }
            {   // B tile
                bf16x8 v;
#pragma unroll
                for (int j = 0; j < 8; ++j) v[j] = (__bf16)0.f;
                int gn = n0 + row;
                if (gn < N) {
                    const bf16* src = B + (size_t)gn * ldb + k0 + scol;
                    if (k0 + scol + 8 <= K) {
                        v = *(const bf16x8*)src;
                    } else {
#pragma unroll
                        for (int j = 0; j < 8; ++j)
                            if (k0 + scol + j < K) v[j] = ((const __bf16*)src)[j];
                    }
                }
                *(bf16x8*)(&Bs[row * LDSS + scol]) = v;
            }
        }
        __syncthreads();

        const int lm = lane & 15;
        const int lk = (lane >> 4) * 8;
#pragma unroll
        for (int kc = 0; kc < 2; ++kc) {
            bf16x8 af[4], bfr[4];
#pragma unroll
            for (int i = 0; i < 4; ++i)
                af[i] = *(const bf16x8*)(&As[(wm + i * 16 + lm) * LDSS + kc * 32 + lk]);
#pragma unroll
            for (int j = 0; j < 4; ++j)
                bfr[j] = *(const bf16x8*)(&Bs[(wn + j * 16 + lm) * LDSS + kc * 32 + lk]);
#pragma unroll
            for (int i = 0; i < 4; ++i)
#pragma unroll
                for (int j = 0; j < 4; ++j)
                    acc[i][j] = __builtin_amdgcn_mfma_f32_16x16x32_bf16(af[i], bfr[j], acc[i][j], 0, 0, 0);
        }
        __syncthreads();
    }

    // D layout: col=lane&15, row=(lane>>4)*4+r  [m89/m91 verified]
    const int col = lane & 15;
    const int rbase = (lane >> 4) * 4;
#pragma unroll
    for (int i = 0; i < 4; ++i) {
#pragma unroll
        for (int j = 0; j < 4; ++j) {
            int gn = n0 + wn + j * 16 + col;
            if (gn >= N) continue;
#pragma unroll
            for (int r = 0; r < 4; ++r) {
                int gm = m0 + wm + i * 16 + rbase + r;
                if (gm >= M) continue;
                float v = acc[i][j][r];
                if (ACT == 1) {
                    v += bias[gn];
                    v = (v > 20.f) ? v : log1pf(__expf(v));
                }
                C[(size_t)gm * ldc + gn] = f2bf(v);
            }
        }
    }
}

// depthwise causal conv(4) + bias + SiLU.  xz bf16 [BL,3072]; u = cols 0..1535.
__global__ __launch_bounds__(256) void conv_silu_kernel(
    const bf16* __restrict__ xz, const float* __restrict__ w,
    const float* __restrict__ cb, bf16* __restrict__ uc_b, int BL, int L)
{
    int idx = blockIdx.x * 256 + threadIdx.x;   // over BL*1536
    if (idx >= BL * 1536) return;
    int d  = idx % 1536;
    int bt = idx / 1536;
    int t  = bt % L;
    float acc = cb[d];
#pragma unroll
    for (int j = 0; j < 4; ++j) {
        int tt = t - 3 + j;
        if (tt >= 0)
            acc += bf2f(xz[(size_t)(bt - 3 + j) * 3072 + d]) * w[d * 4 + j];
    }
    float s = acc / (1.f + __expf(-acc));
    uc_b[idx] = f2bf(s);
}

// selective scan: one wave handles 4 channels x 16 states. lane = dl*16 + n.
__global__ __launch_bounds__(64) void scan_kernel(
    const bf16* __restrict__ dt, const bf16* __restrict__ u,
    const bf16* __restrict__ xdbl, const float* __restrict__ A_log,
    const float* __restrict__ Dp, const bf16* __restrict__ xz,
    bf16* __restrict__ y, int L)
{
    const int lane = threadIdx.x;
    const int n  = lane & 15;
    const int dl = lane >> 4;
    const int blk = blockIdx.x;            // 0 .. 2*384-1
    const int b = blk / 384;
    const int d = (blk % 384) * 4 + dl;

    const float Av = -__expf(A_log[d * 16 + n]);
    const float Dv = Dp[d];
    float h = 0.f;
    const size_t base = (size_t)b * L;

    for (int t = 0; t < L; ++t) {
        const size_t row = base + t;
        float dtv = bf2f(dt[row * 1536 + d]);
        float uv  = bf2f(u[row * 1536 + d]);
        float Bv  = bf2f(xdbl[row * 80 + 48 + n]);
        float Cv  = bf2f(xdbl[row * 80 + 64 + n]);
        float dA  = __expf(dtv * Av);
        h = h * dA + dtv * uv * Bv;
        float p = h * Cv;
        p += __shfl_xor(p, 1, 16);
        p += __shfl_xor(p, 2, 16);
        p += __shfl_xor(p, 4, 16);
        p += __shfl_xor(p, 8, 16);
        if (n == 0) {
            float zv = bf2f(xz[row * 3072 + 1536 + d]);
            float g  = zv / (1.f + __expf(-zv));
            y[row * 1536 + d] = f2bf((p + uv * Dv) * g);
        }
    }
}

// residual add + LayerNorm over 768 (f32 in/out), one block per row
__global__ __launch_bounds__(256) void ln_kernel(
    const bf16* __restrict__ outmm, const float* __restrict__ x,
    const float* __restrict__ w, const float* __restrict__ bsk,
    float* __restrict__ out)
{
    __shared__ float red[2][4];
    const int row = blockIdx.x;
    const int tid = threadIdx.x;
    const bf16* po = outmm + (size_t)row * 768;
    const float* px = x + (size_t)row * 768;
    float vals[3];
    float s = 0.f, s2 = 0.f;
#pragma unroll
    for (int i = 0; i < 3; ++i) {
        int c = tid + i * 256;
        float h = bf2f(po[c]) + px[c];
        vals[i] = h; s += h; s2 += h * h;
    }
#pragma unroll
    for (int o = 32; o >= 1; o >>= 1) { s += __shfl_xor(s, o, 64); s2 += __shfl_xor(s2, o, 64); }
    const int wave = tid >> 6;
    if ((tid & 63) == 0) { red[0][wave] = s; red[1][wave] = s2; }
    __syncthreads();
    s  = red[0][0] + red[0][1] + red[0][2] + red[0][3];
    s2 = red[1][0] + red[1][1] + red[1][2] + red[1][3];
    const float mu = s * (1.f / 768.f);
    const float var = s2 * (1.f / 768.f) - mu * mu;
    const float rstd = rsqrtf(var + 1e-5f);
    float* pout = out + (size_t)row * 768;
#pragma unroll
    for (int i = 0; i < 3; ++i) {
        int c = tid + i * 256;
        pout[c] = (vals[i] - mu) * rstd * w[c] + bsk[c];
    }
}

extern "C" void kernel_launch(void* const* d_in, const int* in_sizes, int n_in,
                              void* d_out, int out_size, void* d_ws, size_t ws_size,
                              hipStream_t stream)
{
    const float* x_f       = (const float*)d_in[0];   // [2,2048,768]
    const float* in_proj_w = (const float*)d_in[1];   // [3072,768]
    const float* conv_w    = (const float*)d_in[2];   // [1536,1,4]
    const float* conv_b    = (const float*)d_in[3];   // [1536]
    const float* x_proj_w  = (const float*)d_in[4];   // [80,1536]
    const float* dt_proj_w = (const float*)d_in[5];   // [1536,48]
    const float* dt_proj_b = (const float*)d_in[6];   // [1536]
    const float* A_log     = (const float*)d_in[7];   // [1536,16]
    const float* Dp        = (const float*)d_in[8];   // [1536]
    const float* out_proj_w= (const float*)d_in[9];   // [768,1536]
    const float* ln_w      = (const float*)d_in[10];  // [768]
    const float* ln_b      = (const float*)d_in[11];  // [768]
    float* out = (float*)d_out;

    const int L = 2048, BL = 4096;

    char* ws = (char*)d_ws;
    size_t off = 0;
    bf16* xbf  = (bf16*)(ws + off); off += (size_t)BL * 768 * 2;      // 6.29 MB
    bf16* wip  = (bf16*)(ws + off); off += (size_t)3072 * 768 * 2;    // 4.72 MB
    bf16* wxp  = (bf16*)(ws + off); off += (size_t)80 * 1536 * 2;     // 0.25 MB
    bf16* wdt  = (bf16*)(ws + off); off += (size_t)1536 * 48 * 2;     // 0.15 MB
    bf16* wop  = (bf16*)(ws + off); off += (size_t)768 * 1536 * 2;    // 2.36 MB
    bf16* xz   = (bf16*)(ws + off); off += (size_t)BL * 3072 * 2;     // 25.2 MB
    bf16* ucb  = (bf16*)(ws + off); off += (size_t)BL * 1536 * 2;     // 12.6 MB
    bf16* xdbl = (bf16*)(ws + off); off += (size_t)BL * 80 * 2;       // 0.66 MB
    bf16* dtb  = (bf16*)(ws + off); off += (size_t)BL * 1536 * 2;     // 12.6 MB
    bf16* yb   = (bf16*)(ws + off); off += (size_t)BL * 1536 * 2;     // 12.6 MB
    bf16* outmm= (bf16*)(ws + off); off += (size_t)BL * 768 * 2;      // 6.29 MB
    // total ~83.7 MB

    // 0. convert f32 inputs -> bf16 (GEMM operands only)
    auto cvt = [&](const float* s, bf16* d, int n) {
        int n4 = n / 4;
        f2b_kernel<<<(n4 + 255) / 256, 256, 0, stream>>>(s, d, n4);
    };
    cvt(x_f,        xbf, BL * 768);
    cvt(in_proj_w,  wip, 3072 * 768);
    cvt(x_proj_w,   wxp, 80 * 1536);
    cvt(dt_proj_w,  wdt, 1536 * 48);
    cvt(out_proj_w, wop, 768 * 1536);

    // 1. xz = x @ in_proj_w^T   [4096,3072]
    gemm_bt<0><<<dim3(32, 24), 256, 0, stream>>>(xbf, wip, nullptr, xz,
                                                 BL, 3072, 768, 768, 768, 3072);
    // 2. depthwise conv + SiLU -> u (bf16)
    conv_silu_kernel<<<(BL * 1536) / 256, 256, 0, stream>>>(xz, conv_w, conv_b, ucb, BL, L);
    // 3. x_dbl = u @ x_proj_w^T  [4096,80]
    gemm_bt<0><<<dim3(32, 1), 256, 0, stream>>>(ucb, wxp, nullptr, xdbl,
                                                BL, 80, 1536, 1536, 1536, 80);
    // 4. dt = softplus(dtl @ dt_proj_w^T + b)  [4096,1536]  (K=48, lda=80)
    gemm_bt<1><<<dim3(32, 12), 256, 0, stream>>>(xdbl, wdt, dt_proj_b, dtb,
                                                 BL, 1536, 48, 80, 48, 1536);
    // 5. selective scan -> y gated  [4096,1536]
    scan_kernel<<<768, 64, 0, stream>>>(dtb, ucb, xdbl, A_log, Dp, xz, yb, L);
    // 6. out = y @ out_proj_w^T  [4096,768]
    gemm_bt<0><<<dim3(32, 6), 256, 0, stream>>>(yb, wop, nullptr, outmm,
                                                BL, 768, 1536, 1536, 1536, 768);
    // 7. residual + LayerNorm (f32)
    ln_kernel<<<BL, 256, 0, stream>>>(outmm, x_f, ln_w, ln_b, out);
}

// Round 3
// 582.584 us; speedup vs baseline: 3.1046x; 3.1046x over previous
//
#include <hip/hip_runtime.h>
#include <hip/hip_bf16.h>
#include <stdint.h>

typedef __hip_bfloat16 bf16;
typedef __attribute__((ext_vector_type(8))) __bf16 bf16x8;
typedef __attribute__((ext_vector_type(4))) float f32x4;

__device__ __forceinline__ float bf2f(bf16 v) { return __bfloat162float(v); }
__device__ __forceinline__ bf16 f2bf(float v) { return __float2bfloat16(v); }

struct bf4 { bf16 a, b, c, d; };

// f32 -> bf16 converter, 4 elems/thread
__global__ __launch_bounds__(256) void f2b_kernel(
    const float* __restrict__ s, bf16* __restrict__ d, int n4)
{
    int i = blockIdx.x * 256 + threadIdx.x;
    if (i >= n4) return;
    float4 v = ((const float4*)s)[i];
    bf4 o;
    o.a = f2bf(v.x); o.b = f2bf(v.y); o.c = f2bf(v.z); o.d = f2bf(v.w);
    ((bf4*)d)[i] = o;
}

#define BM 128
#define BN 128
#define BK 64
#define LDSS 72

template <int ACT>
__global__ __launch_bounds__(256) void gemm_bt(
    const bf16* __restrict__ A, const bf16* __restrict__ B,
    const float* __restrict__ bias, bf16* __restrict__ C,
    int M, int N, int K, int lda, int ldb, int ldc)
{
    __shared__ bf16 As[BM * LDSS];
    __shared__ bf16 Bs[BN * LDSS];

    const int tid  = threadIdx.x;
    const int wave = tid >> 6;
    const int lane = tid & 63;
    const int m0 = blockIdx.x * BM;
    const int n0 = blockIdx.y * BN;
    const int wm = (wave >> 1) * 64;
    const int wn = (wave & 1) * 64;

    f32x4 acc[4][4];
#pragma unroll
    for (int i = 0; i < 4; ++i)
#pragma unroll
        for (int j = 0; j < 4; ++j)
#pragma unroll
            for (int r = 0; r < 4; ++r) acc[i][j][r] = 0.f;

    const int srow = tid >> 3;
    const int scol = (tid & 7) * 8;

    for (int k0 = 0; k0 < K; k0 += BK) {
#pragma unroll
        for (int p = 0; p < 4; ++p) {
            int row = p * 32 + srow;
            {   // A tile
                bf16x8 v;
#pragma unroll
                for (int j = 0; j < 8; ++j) v[j] = (__bf16)0.f;
                int gm = m0 + row;
                if (gm < M) {
                    const bf16* src = A + (size_t)gm * lda + k0 + scol;
                    if (k0 + scol + 8 <= K) {
                        v = *(const bf16x8*)src;
                    } else {
#pragma unroll
                        for (int j = 0; j < 8; ++j)
                            if (k0 + scol + j < K) v[j] = ((const __bf16*)src)[j];
                    }
                }
                *(bf16x8*)(&As[row * LDSS + scol]) = v;
            }
            {   // B tile
                bf16x8 v;
#pragma unroll
                for (int j = 0; j < 8; ++j) v[j] = (__bf16)0.f;
                int gn = n0 + row;
                if (gn < N) {
                    const bf16* src = B + (size_t)gn * ldb + k0 + scol;
                    if (k0 + scol + 8 <= K) {
                        v = *(const bf16x8*)src;
                    } else {
#pragma unroll
                        for (int j = 0; j < 8; ++j)
                            if (k0 + scol + j < K) v[j] = ((const __bf16*)src)[j];
                    }
                }
                *(bf16x8*)(&Bs[row * LDSS + scol]) = v;
            }
        }
        __syncthreads();

        const int lm = lane & 15;
        const int lk = (lane >> 4) * 8;
#pragma unroll
        for (int kc = 0; kc < 2; ++kc) {
            bf16x8 af[4], bfr[4];
#pragma unroll
            for (int i = 0; i < 4; ++i)
                af[i] = *(const bf16x8*)(&As[(wm + i * 16 + lm) * LDSS + kc * 32 + lk]);
#pragma unroll
            for (int j = 0; j < 4; ++j)
                bfr[j] = *(const bf16x8*)(&Bs[(wn + j * 16 + lm) * LDSS + kc * 32 + lk]);
#pragma unroll
            for (int i = 0; i < 4; ++i)
#pragma unroll
                for (int j = 0; j < 4; ++j)
                    acc[i][j] = __builtin_amdgcn_mfma_f32_16x16x32_bf16(af[i], bfr[j], acc[i][j], 0, 0, 0);
        }
        __syncthreads();
    }

    const int col = lane & 15;
    const int rbase = (lane >> 4) * 4;
#pragma unroll
    for (int i = 0; i < 4; ++i) {
#pragma unroll
        for (int j = 0; j < 4; ++j) {
            int gn = n0 + wn + j * 16 + col;
            if (gn >= N) continue;
#pragma unroll
            for (int r = 0; r < 4; ++r) {
                int gm = m0 + wm + i * 16 + rbase + r;
                if (gm >= M) continue;
                float v = acc[i][j][r];
                if (ACT == 1) {
                    v += bias[gn];
                    v = (v > 20.f) ? v : log1pf(__expf(v));
                }
                C[(size_t)gm * ldc + gn] = f2bf(v);
            }
        }
    }
}

// depthwise causal conv(4) + bias + SiLU
__global__ __launch_bounds__(256) void conv_silu_kernel(
    const bf16* __restrict__ xz, const float* __restrict__ w,
    const float* __restrict__ cb, bf16* __restrict__ uc_b, int BL, int L)
{
    int idx = blockIdx.x * 256 + threadIdx.x;
    if (idx >= BL * 1536) return;
    int d  = idx % 1536;
    int bt = idx / 1536;
    int t  = bt % L;
    float acc = cb[d];
#pragma unroll
    for (int j = 0; j < 4; ++j) {
        int tt = t - 3 + j;
        if (tt >= 0)
            acc += bf2f(xz[(size_t)(bt - 3 + j) * 3072 + d]) * w[d * 4 + j];
    }
    float s = acc / (1.f + __expf(-acc));
    uc_b[idx] = f2bf(s);
}

// ---- chunked selective scan: L=2048 -> 32 chunks x 64 steps ----
#define NCH 32
#define CL  64
#define NGRP 768          // 2 batches * 384 d-groups (4 channels each)
#define NBDN 49152        // 2*1536*16

// pass1: local scan from h=0; emit per-lane (prod dA, h_end)
__global__ __launch_bounds__(256) void scan_pass1(
    const bf16* __restrict__ dt, const bf16* __restrict__ u,
    const bf16* __restrict__ xdbl, const float* __restrict__ A_log,
    float* __restrict__ hend, float* __restrict__ aprod, int L)
{
    const int wave = threadIdx.x >> 6, lane = threadIdx.x & 63;
    const int n = lane & 15, dl = lane >> 4;
    const int grp = blockIdx.x * 4 + wave;     // 0..767
    const int c = blockIdx.y;
    const int b = grp / 384;
    const int d = (grp % 384) * 4 + dl;

    const float Av = -__expf(A_log[d * 16 + n]);
    float h = 0.f, ap = 1.f;
    const size_t base = (size_t)b * L + c * CL;
    for (int t = 0; t < CL; ++t) {
        const size_t row = base + t;
        float dtv = bf2f(dt[row * 1536 + d]);
        float uv  = bf2f(u[row * 1536 + d]);
        float Bv  = bf2f(xdbl[row * 80 + 48 + n]);
        float dA  = __expf(dtv * Av);
        h = h * dA + dtv * uv * Bv;
        ap *= dA;
    }
    const int idx = c * NBDN + grp * 64 + lane;
    hend[idx] = h;
    aprod[idx] = ap;
}

// pass2: sequential combine over the 32 chunks -> initial state per chunk
__global__ __launch_bounds__(256) void scan_pass2(
    const float* __restrict__ hend, const float* __restrict__ aprod,
    float* __restrict__ hinit)
{
    const int i = blockIdx.x * 256 + threadIdx.x;   // 0..49151
    float h = 0.f;
#pragma unroll
    for (int c = 0; c < NCH; ++c) {
        hinit[c * NBDN + i] = h;
        h = aprod[c * NBDN + i] * h + hend[c * NBDN + i];
    }
}

// pass3: rescan chunk from hinit; C-dot, skip, gate, store y
__global__ __launch_bounds__(256) void scan_pass3(
    const bf16* __restrict__ dt, const bf16* __restrict__ u,
    const bf16* __restrict__ xdbl, const float* __restrict__ A_log,
    const float* __restrict__ Dp, const bf16* __restrict__ xz,
    const float* __restrict__ hinit, bf16* __restrict__ y, int L)
{
    const int wave = threadIdx.x >> 6, lane = threadIdx.x & 63;
    const int n = lane & 15, dl = lane >> 4;
    const int grp = blockIdx.x * 4 + wave;
    const int c = blockIdx.y;
    const int b = grp / 384;
    const int d = (grp % 384) * 4 + dl;

    const float Av = -__expf(A_log[d * 16 + n]);
    const float Dv = Dp[d];
    float h = hinit[c * NBDN + grp * 64 + lane];
    const size_t base = (size_t)b * L + c * CL;
    for (int t = 0; t < CL; ++t) {
        const size_t row = base + t;
        float dtv = bf2f(dt[row * 1536 + d]);
        float uv  = bf2f(u[row * 1536 + d]);
        float Bv  = bf2f(xdbl[row * 80 + 48 + n]);
        float Cv  = bf2f(xdbl[row * 80 + 64 + n]);
        float dA  = __expf(dtv * Av);
        h = h * dA + dtv * uv * Bv;
        float p = h * Cv;
        p += __shfl_xor(p, 1, 16);
        p += __shfl_xor(p, 2, 16);
        p += __shfl_xor(p, 4, 16);
        p += __shfl_xor(p, 8, 16);
        if (n == 0) {
            float zv = bf2f(xz[row * 3072 + 1536 + d]);
            float g  = zv / (1.f + __expf(-zv));
            y[row * 1536 + d] = f2bf((p + uv * Dv) * g);
        }
    }
}

// residual + LayerNorm over 768 (f32 in/out)
__global__ __launch_bounds__(256) void ln_kernel(
    const bf16* __restrict__ outmm, const float* __restrict__ x,
    const float* __restrict__ w, const float* __restrict__ bsk,
    float* __restrict__ out)
{
    __shared__ float red[2][4];
    const int row = blockIdx.x;
    const int tid = threadIdx.x;
    const bf16* po = outmm + (size_t)row * 768;
    const float* px = x + (size_t)row * 768;
    float vals[3];
    float s = 0.f, s2 = 0.f;
#pragma unroll
    for (int i = 0; i < 3; ++i) {
        int c = tid + i * 256;
        float h = bf2f(po[c]) + px[c];
        vals[i] = h; s += h; s2 += h * h;
    }
#pragma unroll
    for (int o = 32; o >= 1; o >>= 1) { s += __shfl_xor(s, o, 64); s2 += __shfl_xor(s2, o, 64); }
    const int wave = tid >> 6;
    if ((tid & 63) == 0) { red[0][wave] = s; red[1][wave] = s2; }
    __syncthreads();
    s  = red[0][0] + red[0][1] + red[0][2] + red[0][3];
    s2 = red[1][0] + red[1][1] + red[1][2] + red[1][3];
    const float mu = s * (1.f / 768.f);
    const float var = s2 * (1.f / 768.f) - mu * mu;
    const float rstd = rsqrtf(var + 1e-5f);
    float* pout = out + (size_t)row * 768;
#pragma unroll
    for (int i = 0; i < 3; ++i) {
        int c = tid + i * 256;
        pout[c] = (vals[i] - mu) * rstd * w[c] + bsk[c];
    }
}

extern "C" void kernel_launch(void* const* d_in, const int* in_sizes, int n_in,
                              void* d_out, int out_size, void* d_ws, size_t ws_size,
                              hipStream_t stream)
{
    const float* x_f       = (const float*)d_in[0];
    const float* in_proj_w = (const float*)d_in[1];
    const float* conv_w    = (const float*)d_in[2];
    const float* conv_b    = (const float*)d_in[3];
    const float* x_proj_w  = (const float*)d_in[4];
    const float* dt_proj_w = (const float*)d_in[5];
    const float* dt_proj_b = (const float*)d_in[6];
    const float* A_log     = (const float*)d_in[7];
    const float* Dp        = (const float*)d_in[8];
    const float* out_proj_w= (const float*)d_in[9];
    const float* ln_w      = (const float*)d_in[10];
    const float* ln_b      = (const float*)d_in[11];
    float* out = (float*)d_out;

    const int L = 2048, BL = 4096;

    char* ws = (char*)d_ws;
    size_t off = 0;
    bf16* xbf  = (bf16*)(ws + off); off += (size_t)BL * 768 * 2;      // 6.29 MB (reused as aprod after gemm1)
    bf16* wip  = (bf16*)(ws + off); off += (size_t)3072 * 768 * 2;
    bf16* wxp  = (bf16*)(ws + off); off += (size_t)80 * 1536 * 2;
    bf16* wdt  = (bf16*)(ws + off); off += (size_t)1536 * 48 * 2;
    bf16* wop  = (bf16*)(ws + off); off += (size_t)768 * 1536 * 2;
    bf16* xz   = (bf16*)(ws + off); off += (size_t)BL * 3072 * 2;
    bf16* ucb  = (bf16*)(ws + off); off += (size_t)BL * 1536 * 2;
    bf16* xdbl = (bf16*)(ws + off); off += (size_t)BL * 80 * 2;
    bf16* dtb  = (bf16*)(ws + off); off += (size_t)BL * 1536 * 2;
    bf16* yb   = (bf16*)(ws + off); off += (size_t)BL * 1536 * 2;
    bf16* outmm= (bf16*)(ws + off); off += (size_t)BL * 768 * 2;      // 6.29 MB (reused as hend before gemm6)
    float* hinit = (float*)(ws + off); off += (size_t)NCH * NBDN * 4; // 6.29 MB
    // total ~90 MB

    // scratch overlays (exact-size fits, lifetime-disjoint):
    float* hend  = (float*)outmm;   // written pass1, read pass2; outmm written later by gemm6
    float* aprod = (float*)xbf;     // written pass1 after gemm1 consumed xbf

    auto cvt = [&](const float* s, bf16* d, int n) {
        int n4 = n / 4;
        f2b_kernel<<<(n4 + 255) / 256, 256, 0, stream>>>(s, d, n4);
    };
    cvt(x_f,        xbf, BL * 768);
    cvt(in_proj_w,  wip, 3072 * 768);
    cvt(x_proj_w,   wxp, 80 * 1536);
    cvt(dt_proj_w,  wdt, 1536 * 48);
    cvt(out_proj_w, wop, 768 * 1536);

    // 1. xz = x @ in_proj_w^T   [4096,3072]
    gemm_bt<0><<<dim3(32, 24), 256, 0, stream>>>(xbf, wip, nullptr, xz,
                                                 BL, 3072, 768, 768, 768, 3072);
    // 2. depthwise conv + SiLU -> u
    conv_silu_kernel<<<(BL * 1536) / 256, 256, 0, stream>>>(xz, conv_w, conv_b, ucb, BL, L);
    // 3. x_dbl = u @ x_proj_w^T  [4096,80]
    gemm_bt<0><<<dim3(32, 1), 256, 0, stream>>>(ucb, wxp, nullptr, xdbl,
                                                BL, 80, 1536, 1536, 1536, 80);
    // 4. dt = softplus(dtl @ dt_proj_w^T + b)  [4096,1536]
    gemm_bt<1><<<dim3(32, 12), 256, 0, stream>>>(xdbl, wdt, dt_proj_b, dtb,
                                                 BL, 1536, 48, 80, 48, 1536);
    // 5. chunked selective scan
    scan_pass1<<<dim3(192, NCH), 256, 0, stream>>>(dtb, ucb, xdbl, A_log, hend, aprod, L);
    scan_pass2<<<NBDN / 256, 256, 0, stream>>>(hend, aprod, hinit);
    scan_pass3<<<dim3(192, NCH), 256, 0, stream>>>(dtb, ucb, xdbl, A_log, Dp, xz, hinit, yb, L);
    // 6. out = y @ out_proj_w^T  [4096,768]
    gemm_bt<0><<<dim3(32, 6), 256, 0, stream>>>(yb, wop, nullptr, outmm,
                                                BL, 768, 1536, 1536, 1536, 768);
    // 7. residual + LayerNorm (f32)
    ln_kernel<<<BL, 256, 0, stream>>>(outmm, x_f, ln_w, ln_b, out);
}

// Round 4
// 488.607 us; speedup vs baseline: 3.7017x; 1.1923x over previous
//
#include <hip/hip_runtime.h>
#include <hip/hip_bf16.h>
#include <stdint.h>

typedef __hip_bfloat16 bf16;
typedef __attribute__((ext_vector_type(8))) __bf16 bf16x8;
typedef __attribute__((ext_vector_type(4))) float f32x4;

__device__ __forceinline__ float bf2f(bf16 v) { return __bfloat162float(v); }
__device__ __forceinline__ bf16 f2bf(float v) { return __float2bfloat16(v); }

struct bf4 { bf16 a, b, c, d; };

// f32 -> bf16 converter, 4 elems/thread
__global__ __launch_bounds__(256) void f2b_kernel(
    const float* __restrict__ s, bf16* __restrict__ d, int n4)
{
    int i = blockIdx.x * 256 + threadIdx.x;
    if (i >= n4) return;
    float4 v = ((const float4*)s)[i];
    bf4 o;
    o.a = f2bf(v.x); o.b = f2bf(v.y); o.c = f2bf(v.z); o.d = f2bf(v.w);
    ((bf4*)d)[i] = o;
}

#define BM 128
#define BN 128
#define BK 64
#define LDSS 72

template <int ACT>
__global__ __launch_bounds__(256) void gemm_bt(
    const bf16* __restrict__ A, const bf16* __restrict__ B,
    const float* __restrict__ bias, bf16* __restrict__ C,
    int M, int N, int K, int lda, int ldb, int ldc)
{
    __shared__ bf16 As[BM * LDSS];
    __shared__ bf16 Bs[BN * LDSS];

    const int tid  = threadIdx.x;
    const int wave = tid >> 6;
    const int lane = tid & 63;
    const int m0 = blockIdx.x * BM;
    const int n0 = blockIdx.y * BN;
    const int wm = (wave >> 1) * 64;
    const int wn = (wave & 1) * 64;

    f32x4 acc[4][4];
#pragma unroll
    for (int i = 0; i < 4; ++i)
#pragma unroll
        for (int j = 0; j < 4; ++j)
#pragma unroll
            for (int r = 0; r < 4; ++r) acc[i][j][r] = 0.f;

    const int srow = tid >> 3;
    const int scol = (tid & 7) * 8;

    for (int k0 = 0; k0 < K; k0 += BK) {
#pragma unroll
        for (int p = 0; p < 4; ++p) {
            int row = p * 32 + srow;
            {   // A tile
                bf16x8 v;
#pragma unroll
                for (int j = 0; j < 8; ++j) v[j] = (__bf16)0.f;
                int gm = m0 + row;
                if (gm < M) {
                    const bf16* src = A + (size_t)gm * lda + k0 + scol;
                    if (k0 + scol + 8 <= K) {
                        v = *(const bf16x8*)src;
                    } else {
#pragma unroll
                        for (int j = 0; j < 8; ++j)
                            if (k0 + scol + j < K) v[j] = ((const __bf16*)src)[j];
                    }
                }
                *(bf16x8*)(&As[row * LDSS + scol]) = v;
            }
            {   // B tile
                bf16x8 v;
#pragma unroll
                for (int j = 0; j < 8; ++j) v[j] = (__bf16)0.f;
                int gn = n0 + row;
                if (gn < N) {
                    const bf16* src = B + (size_t)gn * ldb + k0 + scol;
                    if (k0 + scol + 8 <= K) {
                        v = *(const bf16x8*)src;
                    } else {
#pragma unroll
                        for (int j = 0; j < 8; ++j)
                            if (k0 + scol + j < K) v[j] = ((const __bf16*)src)[j];
                    }
                }
                *(bf16x8*)(&Bs[row * LDSS + scol]) = v;
            }
        }
        __syncthreads();

        const int lm = lane & 15;
        const int lk = (lane >> 4) * 8;
#pragma unroll
        for (int kc = 0; kc < 2; ++kc) {
            bf16x8 af[4], bfr[4];
#pragma unroll
            for (int i = 0; i < 4; ++i)
                af[i] = *(const bf16x8*)(&As[(wm + i * 16 + lm) * LDSS + kc * 32 + lk]);
#pragma unroll
            for (int j = 0; j < 4; ++j)
                bfr[j] = *(const bf16x8*)(&Bs[(wn + j * 16 + lm) * LDSS + kc * 32 + lk]);
#pragma unroll
            for (int i = 0; i < 4; ++i)
#pragma unroll
                for (int j = 0; j < 4; ++j)
                    acc[i][j] = __builtin_amdgcn_mfma_f32_16x16x32_bf16(af[i], bfr[j], acc[i][j], 0, 0, 0);
        }
        __syncthreads();
    }

    const int col = lane & 15;
    const int rbase = (lane >> 4) * 4;
#pragma unroll
    for (int i = 0; i < 4; ++i) {
#pragma unroll
        for (int j = 0; j < 4; ++j) {
            int gn = n0 + wn + j * 16 + col;
            if (gn >= N) continue;
#pragma unroll
            for (int r = 0; r < 4; ++r) {
                int gm = m0 + wm + i * 16 + rbase + r;
                if (gm >= M) continue;
                float v = acc[i][j][r];
                if (ACT == 1) {
                    v += bias[gn];
                    v = (v > 20.f) ? v : log1pf(__expf(v));
                }
                C[(size_t)gm * ldc + gn] = f2bf(v);
            }
        }
    }
}

// depthwise causal conv(4) + bias + SiLU
__global__ __launch_bounds__(256) void conv_silu_kernel(
    const bf16* __restrict__ xz, const float* __restrict__ w,
    const float* __restrict__ cb, bf16* __restrict__ uc_b, int BL, int L)
{
    int idx = blockIdx.x * 256 + threadIdx.x;
    if (idx >= BL * 1536) return;
    int d  = idx % 1536;
    int bt = idx / 1536;
    int t  = bt % L;
    float acc = cb[d];
#pragma unroll
    for (int j = 0; j < 4; ++j) {
        int tt = t - 3 + j;
        if (tt >= 0)
            acc += bf2f(xz[(size_t)(bt - 3 + j) * 3072 + d]) * w[d * 4 + j];
    }
    float s = acc / (1.f + __expf(-acc));
    uc_b[idx] = f2bf(s);
}

// ---- chunked selective scan: L=2048 -> 32 chunks x 64 steps ----
// lane layout: lane = nh*32 + dl32; each lane owns channel d, 8 states (nh half)
#define NCH 32
#define CL  64
#define NBDN 49152        // 2*1536*16
#define LOG2E 1.44269504088896f

// pass1: local scan from h=0; emit per-lane h_end[8] and aprod[8]
__global__ __launch_bounds__(256) void scan_pass1(
    const bf16* __restrict__ dt, const bf16* __restrict__ u,
    const bf16* __restrict__ xdbl, const float* __restrict__ A_log,
    float* __restrict__ hend, float* __restrict__ aprod, int L)
{
    const int wave = threadIdx.x >> 6, lane = threadIdx.x & 63;
    const int nh = lane >> 5, dl = lane & 31;
    const int b = blockIdx.x / 12, dblk = blockIdx.x % 12;
    const int c = blockIdx.y;
    const int d = dblk * 128 + wave * 32 + dl;

    float Av2[8];
#pragma unroll
    for (int n = 0; n < 8; ++n)
        Av2[n] = -__expf(A_log[d * 16 + nh * 8 + n]) * LOG2E;

    float h[8];
#pragma unroll
    for (int n = 0; n < 8; ++n) h[n] = 0.f;
    float sdt = 0.f;

    const size_t base = (size_t)b * L + c * CL;
    for (int t = 0; t < CL; ++t) {
        const size_t row = base + t;
        float dtv = bf2f(dt[row * 1536 + d]);
        float uv  = bf2f(u[row * 1536 + d]);
        float du  = dtv * uv;
        sdt += dtv;
        bf16x8 Bv = *(const bf16x8*)(xdbl + row * 80 + 48 + nh * 8);
#pragma unroll
        for (int n = 0; n < 8; ++n) {
            float dA = exp2f(dtv * Av2[n]);
            h[n] = h[n] * dA + du * (float)Bv[n];
        }
    }
    const size_t idx = ((size_t)c * NBDN) + ((size_t)b * 1536 + d) * 16 + nh * 8;
#pragma unroll
    for (int n = 0; n < 8; ++n) hend[idx + n] = h[n];
#pragma unroll
    for (int n = 0; n < 8; ++n) aprod[idx + n] = exp2f(Av2[n] * sdt);
}

// pass2: sequential combine over chunks -> initial state per chunk
__global__ __launch_bounds__(256) void scan_pass2(
    const float* __restrict__ hend, const float* __restrict__ aprod,
    float* __restrict__ hinit)
{
    const int i = blockIdx.x * 256 + threadIdx.x;   // 0..49151
    float h = 0.f;
#pragma unroll
    for (int c = 0; c < NCH; ++c) {
        hinit[c * NBDN + i] = h;
        h = aprod[c * NBDN + i] * h + hend[c * NBDN + i];
    }
}

// pass3: rescan chunk from hinit; C-dot, skip, gate, store y
__global__ __launch_bounds__(256) void scan_pass3(
    const bf16* __restrict__ dt, const bf16* __restrict__ u,
    const bf16* __restrict__ xdbl, const float* __restrict__ A_log,
    const float* __restrict__ Dp, const bf16* __restrict__ xz,
    const float* __restrict__ hinit, bf16* __restrict__ y, int L)
{
    const int wave = threadIdx.x >> 6, lane = threadIdx.x & 63;
    const int nh = lane >> 5, dl = lane & 31;
    const int b = blockIdx.x / 12, dblk = blockIdx.x % 12;
    const int c = blockIdx.y;
    const int d = dblk * 128 + wave * 32 + dl;

    float Av2[8];
#pragma unroll
    for (int n = 0; n < 8; ++n)
        Av2[n] = -__expf(A_log[d * 16 + nh * 8 + n]) * LOG2E;
    const float Dv = Dp[d];

    const size_t idx = ((size_t)c * NBDN) + ((size_t)b * 1536 + d) * 16 + nh * 8;
    float h[8];
#pragma unroll
    for (int n = 0; n < 8; ++n) h[n] = hinit[idx + n];

    const size_t base = (size_t)b * L + c * CL;
    for (int t = 0; t < CL; ++t) {
        const size_t row = base + t;
        float dtv = bf2f(dt[row * 1536 + d]);
        float uv  = bf2f(u[row * 1536 + d]);
        float du  = dtv * uv;
        bf16x8 Bv = *(const bf16x8*)(xdbl + row * 80 + 48 + nh * 8);
        bf16x8 Cv = *(const bf16x8*)(xdbl + row * 80 + 64 + nh * 8);
        float p = 0.f;
#pragma unroll
        for (int n = 0; n < 8; ++n) {
            float dA = exp2f(dtv * Av2[n]);
            h[n] = h[n] * dA + du * (float)Bv[n];
            p += h[n] * (float)Cv[n];
        }
        p += __shfl_xor(p, 32, 64);
        if (nh == 0) {
            float zv = bf2f(xz[row * 3072 + 1536 + d]);
            float g  = zv / (1.f + __expf(-zv));
            y[row * 1536 + d] = f2bf((p + uv * Dv) * g);
        }
    }
}

// residual + LayerNorm over 768 (f32 in/out)
__global__ __launch_bounds__(256) void ln_kernel(
    const bf16* __restrict__ outmm, const float* __restrict__ x,
    const float* __restrict__ w, const float* __restrict__ bsk,
    float* __restrict__ out)
{
    __shared__ float red[2][4];
    const int row = blockIdx.x;
    const int tid = threadIdx.x;
    const bf16* po = outmm + (size_t)row * 768;
    const float* px = x + (size_t)row * 768;
    float vals[3];
    float s = 0.f, s2 = 0.f;
#pragma unroll
    for (int i = 0; i < 3; ++i) {
        int c = tid + i * 256;
        float h = bf2f(po[c]) + px[c];
        vals[i] = h; s += h; s2 += h * h;
    }
#pragma unroll
    for (int o = 32; o >= 1; o >>= 1) { s += __shfl_xor(s, o, 64); s2 += __shfl_xor(s2, o, 64); }
    const int wave = tid >> 6;
    if ((tid & 63) == 0) { red[0][wave] = s; red[1][wave] = s2; }
    __syncthreads();
    s  = red[0][0] + red[0][1] + red[0][2] + red[0][3];
    s2 = red[1][0] + red[1][1] + red[1][2] + red[1][3];
    const float mu = s * (1.f / 768.f);
    const float var = s2 * (1.f / 768.f) - mu * mu;
    const float rstd = rsqrtf(var + 1e-5f);
    float* pout = out + (size_t)row * 768;
#pragma unroll
    for (int i = 0; i < 3; ++i) {
        int c = tid + i * 256;
        pout[c] = (vals[i] - mu) * rstd * w[c] + bsk[c];
    }
}

extern "C" void kernel_launch(void* const* d_in, const int* in_sizes, int n_in,
                              void* d_out, int out_size, void* d_ws, size_t ws_size,
                              hipStream_t stream)
{
    const float* x_f       = (const float*)d_in[0];
    const float* in_proj_w = (const float*)d_in[1];
    const float* conv_w    = (const float*)d_in[2];
    const float* conv_b    = (const float*)d_in[3];
    const float* x_proj_w  = (const float*)d_in[4];
    const float* dt_proj_w = (const float*)d_in[5];
    const float* dt_proj_b = (const float*)d_in[6];
    const float* A_log     = (const float*)d_in[7];
    const float* Dp        = (const float*)d_in[8];
    const float* out_proj_w= (const float*)d_in[9];
    const float* ln_w      = (const float*)d_in[10];
    const float* ln_b      = (const float*)d_in[11];
    float* out = (float*)d_out;

    const int L = 2048, BL = 4096;

    char* ws = (char*)d_ws;
    size_t off = 0;
    bf16* xbf  = (bf16*)(ws + off); off += (size_t)BL * 768 * 2;      // reused as aprod after gemm1
    bf16* wip  = (bf16*)(ws + off); off += (size_t)3072 * 768 * 2;
    bf16* wxp  = (bf16*)(ws + off); off += (size_t)80 * 1536 * 2;
    bf16* wdt  = (bf16*)(ws + off); off += (size_t)1536 * 48 * 2;
    bf16* wop  = (bf16*)(ws + off); off += (size_t)768 * 1536 * 2;
    bf16* xz   = (bf16*)(ws + off); off += (size_t)BL * 3072 * 2;
    bf16* ucb  = (bf16*)(ws + off); off += (size_t)BL * 1536 * 2;
    bf16* xdbl = (bf16*)(ws + off); off += (size_t)BL * 80 * 2;
    bf16* dtb  = (bf16*)(ws + off); off += (size_t)BL * 1536 * 2;
    bf16* yb   = (bf16*)(ws + off); off += (size_t)BL * 1536 * 2;
    bf16* outmm= (bf16*)(ws + off); off += (size_t)BL * 768 * 2;      // reused as hend before gemm6
    float* hinit = (float*)(ws + off); off += (size_t)NCH * NBDN * 4;

    float* hend  = (float*)outmm;   // pass1 write -> pass2 read; dead before gemm6
    float* aprod = (float*)xbf;     // pass1 write -> pass2 read; xbf dead after gemm1

    auto cvt = [&](const float* s, bf16* d, int n) {
        int n4 = n / 4;
        f2b_kernel<<<(n4 + 255) / 256, 256, 0, stream>>>(s, d, n4);
    };
    cvt(x_f,        xbf, BL * 768);
    cvt(in_proj_w,  wip, 3072 * 768);
    cvt(x_proj_w,   wxp, 80 * 1536);
    cvt(dt_proj_w,  wdt, 1536 * 48);
    cvt(out_proj_w, wop, 768 * 1536);

    // 1. xz = x @ in_proj_w^T   [4096,3072]
    gemm_bt<0><<<dim3(32, 24), 256, 0, stream>>>(xbf, wip, nullptr, xz,
                                                 BL, 3072, 768, 768, 768, 3072);
    // 2. depthwise conv + SiLU -> u
    conv_silu_kernel<<<(BL * 1536) / 256, 256, 0, stream>>>(xz, conv_w, conv_b, ucb, BL, L);
    // 3. x_dbl = u @ x_proj_w^T  [4096,80]
    gemm_bt<0><<<dim3(32, 1), 256, 0, stream>>>(ucb, wxp, nullptr, xdbl,
                                                BL, 80, 1536, 1536, 1536, 80);
    // 4. dt = softplus(dtl @ dt_proj_w^T + b)  [4096,1536]
    gemm_bt<1><<<dim3(32, 12), 256, 0, stream>>>(xdbl, wdt, dt_proj_b, dtb,
                                                 BL, 1536, 48, 80, 48, 1536);
    // 5. chunked selective scan (lane-per-channel, 8 states/lane)
    scan_pass1<<<dim3(24, NCH), 256, 0, stream>>>(dtb, ucb, xdbl, A_log, hend, aprod, L);
    scan_pass2<<<NBDN / 256, 256, 0, stream>>>(hend, aprod, hinit);
    scan_pass3<<<dim3(24, NCH), 256, 0, stream>>>(dtb, ucb, xdbl, A_log, Dp, xz, hinit, yb, L);
    // 6. out = y @ out_proj_w^T  [4096,768]
    gemm_bt<0><<<dim3(32, 6), 256, 0, stream>>>(yb, wop, nullptr, outmm,
                                                BL, 768, 1536, 1536, 1536, 768);
    // 7. residual + LayerNorm (f32)
    ln_kernel<<<BL, 256, 0, stream>>>(outmm, x_f, ln_w, ln_b, out);
}

// Round 5
// 421.482 us; speedup vs baseline: 4.2913x; 1.1593x over previous
//
#include <hip/hip_runtime.h>
#include <hip/hip_bf16.h>
#include <stdint.h>

typedef __hip_bfloat16 bf16;
typedef __attribute__((ext_vector_type(8))) __bf16 bf16x8;
typedef __attribute__((ext_vector_type(4))) float f32x4;

__device__ __forceinline__ float bf2f(bf16 v) { return __bfloat162float(v); }
__device__ __forceinline__ bf16 f2bf(float v) { return __float2bfloat16(v); }

struct bf4 { bf16 a, b, c, d; };

// f32 -> bf16 converter, 4 elems/thread
__global__ __launch_bounds__(256) void f2b_kernel(
    const float* __restrict__ s, bf16* __restrict__ d, int n4)
{
    int i = blockIdx.x * 256 + threadIdx.x;
    if (i >= n4) return;
    float4 v = ((const float4*)s)[i];
    bf4 o;
    o.a = f2bf(v.x); o.b = f2bf(v.y); o.c = f2bf(v.z); o.d = f2bf(v.w);
    ((bf4*)d)[i] = o;
}

#define BM 128
#define BK 64
#define LDSS 72

// C[m,n] = sum_k A[m,k]*B[n,k]. TBN = n-tile (128 or 64).
// If C32 != nullptr: write f32 partials at C32[(z*M + m)*ldc + n] (split-K over blockIdx.z).
// ACT==1: C = softplus(v + bias[n]) (only when C32==nullptr).
template <int ACT, int TBN>
__global__ __launch_bounds__(256) void gemm_bt(
    const bf16* __restrict__ A, const bf16* __restrict__ B,
    const float* __restrict__ bias, bf16* __restrict__ C, float* __restrict__ C32,
    int M, int N, int K, int lda, int ldb, int ldc)
{
    constexpr int NJ = TBN / 32;          // n-frags per wave
    __shared__ bf16 As[BM * LDSS];
    __shared__ bf16 Bs[TBN * LDSS];

    const int tid  = threadIdx.x;
    const int wave = tid >> 6;
    const int lane = tid & 63;
    const int m0 = blockIdx.x * BM;
    const int n0 = blockIdx.y * TBN;
    const int wm = (wave >> 1) * 64;
    const int wn = (wave & 1) * (TBN / 2);

    f32x4 acc[4][NJ];
#pragma unroll
    for (int i = 0; i < 4; ++i)
#pragma unroll
        for (int j = 0; j < NJ; ++j)
#pragma unroll
            for (int r = 0; r < 4; ++r) acc[i][j][r] = 0.f;

    const int srow = tid >> 3;
    const int scol = (tid & 7) * 8;

    const int kz = K / gridDim.z;
    const int kbeg = blockIdx.z * kz;
    const int kend = kbeg + kz;

    for (int k0 = kbeg; k0 < kend; k0 += BK) {
#pragma unroll
        for (int p = 0; p < 4; ++p) {     // A tile: 128 rows
            int row = p * 32 + srow;
            bf16x8 v;
#pragma unroll
            for (int j = 0; j < 8; ++j) v[j] = (__bf16)0.f;
            int gm = m0 + row;
            if (gm < M) {
                const bf16* src = A + (size_t)gm * lda + k0 + scol;
                if (k0 + scol + 8 <= K) {
                    v = *(const bf16x8*)src;
                } else {
#pragma unroll
                    for (int j = 0; j < 8; ++j)
                        if (k0 + scol + j < K) v[j] = ((const __bf16*)src)[j];
                }
            }
            *(bf16x8*)(&As[row * LDSS + scol]) = v;
        }
#pragma unroll
        for (int p = 0; p < TBN / 32; ++p) {  // B tile: TBN rows
            int row = p * 32 + srow;
            bf16x8 v;
#pragma unroll
            for (int j = 0; j < 8; ++j) v[j] = (__bf16)0.f;
            int gn = n0 + row;
            if (gn < N) {
                const bf16* src = B + (size_t)gn * ldb + k0 + scol;
                if (k0 + scol + 8 <= K) {
                    v = *(const bf16x8*)src;
                } else {
#pragma unroll
                    for (int j = 0; j < 8; ++j)
                        if (k0 + scol + j < K) v[j] = ((const __bf16*)src)[j];
                }
            }
            *(bf16x8*)(&Bs[row * LDSS + scol]) = v;
        }
        __syncthreads();

        const int lm = lane & 15;
        const int lk = (lane >> 4) * 8;
#pragma unroll
        for (int kc = 0; kc < 2; ++kc) {
            bf16x8 af[4], bfr[NJ];
#pragma unroll
            for (int i = 0; i < 4; ++i)
                af[i] = *(const bf16x8*)(&As[(wm + i * 16 + lm) * LDSS + kc * 32 + lk]);
#pragma unroll
            for (int j = 0; j < NJ; ++j)
                bfr[j] = *(const bf16x8*)(&Bs[(wn + j * 16 + lm) * LDSS + kc * 32 + lk]);
#pragma unroll
            for (int i = 0; i < 4; ++i)
#pragma unroll
                for (int j = 0; j < NJ; ++j)
                    acc[i][j] = __builtin_amdgcn_mfma_f32_16x16x32_bf16(af[i], bfr[j], acc[i][j], 0, 0, 0);
        }
        __syncthreads();
    }

    const int col = lane & 15;
    const int rbase = (lane >> 4) * 4;
#pragma unroll
    for (int i = 0; i < 4; ++i) {
#pragma unroll
        for (int j = 0; j < NJ; ++j) {
            int gn = n0 + wn + j * 16 + col;
            if (gn >= N) continue;
#pragma unroll
            for (int r = 0; r < 4; ++r) {
                int gm = m0 + wm + i * 16 + rbase + r;
                if (gm >= M) continue;
                float v = acc[i][j][r];
                if (C32) {
                    C32[((size_t)blockIdx.z * M + gm) * ldc + gn] = v;
                } else {
                    if (ACT == 1) {
                        v += bias[gn];
                        v = (v > 20.f) ? v : log1pf(__expf(v));
                    }
                    C[(size_t)gm * ldc + gn] = f2bf(v);
                }
            }
        }
    }
}

// sum S f32 partials -> bf16
__global__ __launch_bounds__(256) void combine_kernel(
    const float* __restrict__ p, bf16* __restrict__ o, int mn, int S)
{
    int i = blockIdx.x * 256 + threadIdx.x;
    if (i >= mn) return;
    float s = 0.f;
    for (int k = 0; k < S; ++k) s += p[(size_t)k * mn + i];
    o[i] = f2bf(s);
}

// depthwise causal conv(4) + bias + SiLU, 8 channels/thread
__global__ __launch_bounds__(256) void conv_silu_kernel(
    const bf16* __restrict__ xz, const float* __restrict__ w,
    const float* __restrict__ cb, bf16* __restrict__ uc_b, int BL, int L)
{
    int idx = blockIdx.x * 256 + threadIdx.x;   // over BL*192
    if (idx >= BL * 192) return;
    int d8 = (idx % 192) * 8;
    int bt = idx / 192;
    int t  = bt % L;

    float4 wv[8];
#pragma unroll
    for (int n = 0; n < 8; ++n) wv[n] = ((const float4*)w)[d8 + n];

    float acc[8];
#pragma unroll
    for (int n = 0; n < 8; ++n) acc[n] = cb[d8 + n];

#pragma unroll
    for (int j = 0; j < 4; ++j) {
        int tt = t - 3 + j;
        if (tt >= 0) {
            bf16x8 xv = *(const bf16x8*)(xz + (size_t)(bt - 3 + j) * 3072 + d8);
            const float wj0 = ((const float*)&wv[0])[j];
#pragma unroll
            for (int n = 0; n < 8; ++n) {
                float wj = ((const float*)&wv[n])[j];
                acc[n] += (float)xv[n] * wj;
            }
            (void)wj0;
        }
    }
    bf16x8 o;
#pragma unroll
    for (int n = 0; n < 8; ++n) {
        float s = acc[n] / (1.f + __expf(-acc[n]));
        o[n] = (__bf16)s;
    }
    *(bf16x8*)(uc_b + (size_t)bt * 1536 + d8) = o;
}

// ---- chunked selective scan: L=2048 -> 32 chunks x 64 steps ----
#define NCH 32
#define CL  64
#define NBDN 49152        // 2*1536*16
#define LOG2E 1.44269504088896f

__global__ __launch_bounds__(256) void scan_pass1(
    const bf16* __restrict__ dt, const bf16* __restrict__ u,
    const bf16* __restrict__ xdbl, const float* __restrict__ A_log,
    float* __restrict__ hend, float* __restrict__ aprod, int L)
{
    const int wave = threadIdx.x >> 6, lane = threadIdx.x & 63;
    const int nh = lane >> 5, dl = lane & 31;
    const int b = blockIdx.x / 12, dblk = blockIdx.x % 12;
    const int c = blockIdx.y;
    const int d = dblk * 128 + wave * 32 + dl;

    float Av2[8];
#pragma unroll
    for (int n = 0; n < 8; ++n)
        Av2[n] = -__expf(A_log[d * 16 + nh * 8 + n]) * LOG2E;

    float h[8];
#pragma unroll
    for (int n = 0; n < 8; ++n) h[n] = 0.f;
    float sdt = 0.f;

    const size_t base = (size_t)b * L + c * CL;
    for (int t = 0; t < CL; ++t) {
        const size_t row = base + t;
        float dtv = bf2f(dt[row * 1536 + d]);
        float uv  = bf2f(u[row * 1536 + d]);
        float du  = dtv * uv;
        sdt += dtv;
        bf16x8 Bv = *(const bf16x8*)(xdbl + row * 80 + 48 + nh * 8);
#pragma unroll
        for (int n = 0; n < 8; ++n) {
            float dA = exp2f(dtv * Av2[n]);
            h[n] = h[n] * dA + du * (float)Bv[n];
        }
    }
    const size_t idx = ((size_t)c * NBDN) + ((size_t)b * 1536 + d) * 16 + nh * 8;
#pragma unroll
    for (int n = 0; n < 8; ++n) hend[idx + n] = h[n];
#pragma unroll
    for (int n = 0; n < 8; ++n) aprod[idx + n] = exp2f(Av2[n] * sdt);
}

__global__ __launch_bounds__(256) void scan_pass2(
    const float* __restrict__ hend, const float* __restrict__ aprod,
    float* __restrict__ hinit)
{
    const int i = blockIdx.x * 256 + threadIdx.x;   // 0..49151
    float h = 0.f;
#pragma unroll
    for (int c = 0; c < NCH; ++c) {
        hinit[c * NBDN + i] = h;
        h = aprod[c * NBDN + i] * h + hend[c * NBDN + i];
    }
}

__global__ __launch_bounds__(256) void scan_pass3(
    const bf16* __restrict__ dt, const bf16* __restrict__ u,
    const bf16* __restrict__ xdbl, const float* __restrict__ A_log,
    const float* __restrict__ Dp, const bf16* __restrict__ xz,
    const float* __restrict__ hinit, bf16* __restrict__ y, int L)
{
    const int wave = threadIdx.x >> 6, lane = threadIdx.x & 63;
    const int nh = lane >> 5, dl = lane & 31;
    const int b = blockIdx.x / 12, dblk = blockIdx.x % 12;
    const int c = blockIdx.y;
    const int d = dblk * 128 + wave * 32 + dl;

    float Av2[8];
#pragma unroll
    for (int n = 0; n < 8; ++n)
        Av2[n] = -__expf(A_log[d * 16 + nh * 8 + n]) * LOG2E;
    const float Dv = Dp[d];

    const size_t idx = ((size_t)c * NBDN) + ((size_t)b * 1536 + d) * 16 + nh * 8;
    float h[8];
#pragma unroll
    for (int n = 0; n < 8; ++n) h[n] = hinit[idx + n];

    const size_t base = (size_t)b * L + c * CL;
    for (int t = 0; t < CL; ++t) {
        const size_t row = base + t;
        float dtv = bf2f(dt[row * 1536 + d]);
        float uv  = bf2f(u[row * 1536 + d]);
        float du  = dtv * uv;
        bf16x8 Bv = *(const bf16x8*)(xdbl + row * 80 + 48 + nh * 8);
        bf16x8 Cv = *(const bf16x8*)(xdbl + row * 80 + 64 + nh * 8);
        float p = 0.f;
#pragma unroll
        for (int n = 0; n < 8; ++n) {
            float dA = exp2f(dtv * Av2[n]);
            h[n] = h[n] * dA + du * (float)Bv[n];
            p += h[n] * (float)Cv[n];
        }
        p += __shfl_xor(p, 32, 64);
        if (nh == 0) {
            float zv = bf2f(xz[row * 3072 + 1536 + d]);
            float g  = zv / (1.f + __expf(-zv));
            y[row * 1536 + d] = f2bf((p + uv * Dv) * g);
        }
    }
}

// residual + LayerNorm over 768 (f32 in/out)
__global__ __launch_bounds__(256) void ln_kernel(
    const bf16* __restrict__ outmm, const float* __restrict__ x,
    const float* __restrict__ w, const float* __restrict__ bsk,
    float* __restrict__ out)
{
    __shared__ float red[2][4];
    const int row = blockIdx.x;
    const int tid = threadIdx.x;
    const bf16* po = outmm + (size_t)row * 768;
    const float* px = x + (size_t)row * 768;
    float vals[3];
    float s = 0.f, s2 = 0.f;
#pragma unroll
    for (int i = 0; i < 3; ++i) {
        int c = tid + i * 256;
        float h = bf2f(po[c]) + px[c];
        vals[i] = h; s += h; s2 += h * h;
    }
#pragma unroll
    for (int o = 32; o >= 1; o >>= 1) { s += __shfl_xor(s, o, 64); s2 += __shfl_xor(s2, o, 64); }
    const int wave = tid >> 6;
    if ((tid & 63) == 0) { red[0][wave] = s; red[1][wave] = s2; }
    __syncthreads();
    s  = red[0][0] + red[0][1] + red[0][2] + red[0][3];
    s2 = red[1][0] + red[1][1] + red[1][2] + red[1][3];
    const float mu = s * (1.f / 768.f);
    const float var = s2 * (1.f / 768.f) - mu * mu;
    const float rstd = rsqrtf(var + 1e-5f);
    float* pout = out + (size_t)row * 768;
#pragma unroll
    for (int i = 0; i < 3; ++i) {
        int c = tid + i * 256;
        pout[c] = (vals[i] - mu) * rstd * w[c] + bsk[c];
    }
}

extern "C" void kernel_launch(void* const* d_in, const int* in_sizes, int n_in,
                              void* d_out, int out_size, void* d_ws, size_t ws_size,
                              hipStream_t stream)
{
    const float* x_f       = (const float*)d_in[0];
    const float* in_proj_w = (const float*)d_in[1];
    const float* conv_w    = (const float*)d_in[2];
    const float* conv_b    = (const float*)d_in[3];
    const float* x_proj_w  = (const float*)d_in[4];
    const float* dt_proj_w = (const float*)d_in[5];
    const float* dt_proj_b = (const float*)d_in[6];
    const float* A_log     = (const float*)d_in[7];
    const float* Dp        = (const float*)d_in[8];
    const float* out_proj_w= (const float*)d_in[9];
    const float* ln_w      = (const float*)d_in[10];
    const float* ln_b      = (const float*)d_in[11];
    float* out = (float*)d_out;

    const int L = 2048, BL = 4096;

    char* ws = (char*)d_ws;
    size_t off = 0;
    bf16* xbf  = (bf16*)(ws + off); off += (size_t)BL * 768 * 2;      // reused as aprod
    bf16* wip  = (bf16*)(ws + off); off += (size_t)3072 * 768 * 2;
    bf16* wxp  = (bf16*)(ws + off); off += (size_t)80 * 1536 * 2;
    bf16* wdt  = (bf16*)(ws + off); off += (size_t)1536 * 48 * 2;
    bf16* wop  = (bf16*)(ws + off); off += (size_t)768 * 1536 * 2;
    bf16* xz   = (bf16*)(ws + off); off += (size_t)BL * 3072 * 2;
    bf16* ucb  = (bf16*)(ws + off); off += (size_t)BL * 1536 * 2;
    bf16* xdbl = (bf16*)(ws + off); off += (size_t)BL * 80 * 2;
    bf16* dtb  = (bf16*)(ws + off); off += (size_t)BL * 1536 * 2;
    bf16* yb   = (bf16*)(ws + off); off += (size_t)BL * 1536 * 2;     // reused as xdbl32 before pass3
    bf16* outmm= (bf16*)(ws + off); off += (size_t)BL * 768 * 2;      // reused as hend
    float* hinit = (float*)(ws + off); off += (size_t)NCH * NBDN * 4;

    float* hend   = (float*)outmm;  // pass1 -> pass2; dead before gemm6
    float* aprod  = (float*)xbf;    // pass1 -> pass2; xbf dead after gemm1
    float* xdbl32 = (float*)yb;     // gemm3 partials (8*4096*80*4 = 10.5 MB <= 12.6 MB); dead before pass3

    auto cvt = [&](const float* s, bf16* d, int n) {
        int n4 = n / 4;
        f2b_kernel<<<(n4 + 255) / 256, 256, 0, stream>>>(s, d, n4);
    };
    cvt(x_f,        xbf, BL * 768);
    cvt(in_proj_w,  wip, 3072 * 768);
    cvt(x_proj_w,   wxp, 80 * 1536);
    cvt(dt_proj_w,  wdt, 1536 * 48);
    cvt(out_proj_w, wop, 768 * 1536);

    // 1. xz = x @ in_proj_w^T  [4096,3072]
    gemm_bt<0, 128><<<dim3(32, 24, 1), 256, 0, stream>>>(xbf, wip, nullptr, xz, nullptr,
                                                         BL, 3072, 768, 768, 768, 3072);
    // 2. depthwise conv + SiLU -> u  (8 ch/thread)
    conv_silu_kernel<<<(BL * 192) / 256, 256, 0, stream>>>(xz, conv_w, conv_b, ucb, BL, L);
    // 3. x_dbl = u @ x_proj_w^T  [4096,80], split-K=8 -> f32 partials -> combine
    gemm_bt<0, 128><<<dim3(32, 1, 8), 256, 0, stream>>>(ucb, wxp, nullptr, nullptr, xdbl32,
                                                        BL, 80, 1536, 1536, 1536, 80);
    combine_kernel<<<(BL * 80 + 255) / 256, 256, 0, stream>>>(xdbl32, xdbl, BL * 80, 8);
    // 4. dt = softplus(dtl @ dt_proj_w^T + b)  [4096,1536]
    gemm_bt<1, 128><<<dim3(32, 12, 1), 256, 0, stream>>>(xdbl, wdt, dt_proj_b, dtb, nullptr,
                                                         BL, 1536, 48, 80, 48, 1536);
    // 5. chunked selective scan
    scan_pass1<<<dim3(24, NCH), 256, 0, stream>>>(dtb, ucb, xdbl, A_log, hend, aprod, L);
    scan_pass2<<<NBDN / 256, 256, 0, stream>>>(hend, aprod, hinit);
    scan_pass3<<<dim3(24, NCH), 256, 0, stream>>>(dtb, ucb, xdbl, A_log, Dp, xz, hinit, yb, L);
    // 6. out = y @ out_proj_w^T  [4096,768], BN=64 -> 384 blocks
    gemm_bt<0, 64><<<dim3(32, 12, 1), 256, 0, stream>>>(yb, wop, nullptr, outmm, nullptr,
                                                        BL, 768, 1536, 1536, 1536, 768);
    // 7. residual + LayerNorm (f32)
    ln_kernel<<<BL, 256, 0, stream>>>(outmm, x_f, ln_w, ln_b, out);
}